// Round 1
// baseline (684.014 us; speedup 1.0000x reference)
//
#include <hip/hip_runtime.h>
#include <type_traits>

typedef __attribute__((ext_vector_type(8))) short short8;
typedef __attribute__((ext_vector_type(4))) float f32x4;
typedef unsigned short u16;

__device__ __forceinline__ float bf2f(u16 u) {
    union { unsigned int i; float f; } x; x.i = ((unsigned int)u) << 16; return x.f;
}
__device__ __forceinline__ u16 f2bf(float f) {
    union { float f; unsigned int i; } x; x.f = f;
    unsigned int r = x.i + 0x7FFFu + ((x.i >> 16) & 1u);
    return (u16)(r >> 16);
}

// ---------------------------------------------------------------------------
// Weight transpose+concat+bf16 convert: out[n*512 + k] = (k<Ka ? A[k][n] : B[k-Ka][n])
// A,B are [Ka,N]/[512-Ka,N] row-major f32. out is [N,512] bf16 (W^T layout).
// ---------------------------------------------------------------------------
__global__ void transcat_k(u16* __restrict__ out, const float* __restrict__ A,
                           const float* __restrict__ Bm, int N, int Ka) {
    int i = blockIdx.x * blockDim.x + threadIdx.x;
    if (i >= N * 512) return;
    int n = i >> 9, k = i & 511;
    float v = (k < Ka) ? A[k * N + n] : Bm[(k - Ka) * N + n];
    out[i] = f2bf(v);
}

// ---------------------------------------------------------------------------
// Generic MFMA GEMM: C[M,N] = act(A[M,512] @ WT[N,512]^T + bias)
// AT = float (convert to bf16 on stage) or u16 (bf16 raw). ACT: 0 none, 1 relu,
// 2 sigmoid. OT = u16 (bf16) or float. Tile 128x128x64, 4 waves, XOR-swizzled LDS.
// ---------------------------------------------------------------------------
#define BM 128
#define BN 128
#define BK 64

template <typename AT, int ACT, typename OT>
__global__ __launch_bounds__(256) void gemm_k(const AT* __restrict__ A,
                                              const u16* __restrict__ WT,
                                              const float* __restrict__ bias,
                                              OT* __restrict__ C, int M, int N) {
    const int K = 512;
    __shared__ u16 As[BM * BK];
    __shared__ u16 Bs[BN * BK];
    const int t = threadIdx.x;
    const int lane = t & 63;
    const int wid = t >> 6;
    const int wr = wid >> 1, wc = wid & 1;
    const int row_base = blockIdx.x * BM, col_base = blockIdx.y * BN;

    f32x4 acc[4][4] = {};

    for (int kt = 0; kt < K; kt += BK) {
        // stage A tile [128][64] (bf16, XOR swizzle of 8-ushort groups)
        #pragma unroll
        for (int i = t * 4; i < BM * BK; i += 1024) {
            int row = i >> 6, col = i & 63;
            int grow = row_base + row; if (grow >= M) grow = M - 1;
            int li = i ^ ((row & 7) << 3);
            if constexpr (std::is_same<AT, float>::value) {
                float4 v = *(const float4*)&A[(size_t)grow * K + kt + col];
                ushort4 o;
                o.x = f2bf(v.x); o.y = f2bf(v.y); o.z = f2bf(v.z); o.w = f2bf(v.w);
                *(ushort4*)&As[li] = o;
            } else {
                *(ushort4*)&As[li] = *(const ushort4*)&A[(size_t)grow * K + kt + col];
            }
        }
        // stage B tile: WT rows [col_base .. col_base+127], cols [kt .. kt+63]
        #pragma unroll
        for (int i = t * 4; i < BN * BK; i += 1024) {
            int row = i >> 6, col = i & 63;
            int li = i ^ ((row & 7) << 3);
            *(ushort4*)&Bs[li] = *(const ushort4*)&WT[(size_t)(col_base + row) * K + kt + col];
        }
        __syncthreads();
        #pragma unroll
        for (int ks = 0; ks < 2; ++ks) {
            int kk = ks * 32 + (lane >> 4) * 8;
            short8 a[4], b[4];
            #pragma unroll
            for (int mi = 0; mi < 4; ++mi) {
                int r = wr * 64 + mi * 16 + (lane & 15);
                a[mi] = *(const short8*)&As[(r * 64 + kk) ^ ((r & 7) << 3)];
            }
            #pragma unroll
            for (int ni = 0; ni < 4; ++ni) {
                int r = wc * 64 + ni * 16 + (lane & 15);
                b[ni] = *(const short8*)&Bs[(r * 64 + kk) ^ ((r & 7) << 3)];
            }
            #pragma unroll
            for (int mi = 0; mi < 4; ++mi)
                #pragma unroll
                for (int ni = 0; ni < 4; ++ni)
                    acc[mi][ni] = __builtin_amdgcn_mfma_f32_16x16x32_bf16(
                        a[mi], b[ni], acc[mi][ni], 0, 0, 0);
        }
        __syncthreads();
    }

    // epilogue: C/D layout col=lane&15, row=(lane>>4)*4+reg  [m89 verified]
    #pragma unroll
    for (int mi = 0; mi < 4; ++mi) {
        int row0 = row_base + wr * 64 + mi * 16 + ((lane >> 4) << 2);
        #pragma unroll
        for (int ni = 0; ni < 4; ++ni) {
            int col = col_base + wc * 64 + ni * 16 + (lane & 15);
            float bv = bias ? bias[col] : 0.f;
            #pragma unroll
            for (int r = 0; r < 4; ++r) {
                int row = row0 + r;
                if (row < M) {
                    float x = acc[mi][ni][r] + bv;
                    if (ACT == 1) x = fmaxf(x, 0.f);
                    if (ACT == 2) x = 1.f / (1.f + __expf(-x));
                    if constexpr (std::is_same<OT, u16>::value)
                        C[(size_t)row * N + col] = f2bf(x);
                    else
                        C[(size_t)row * N + col] = x;
                }
            }
        }
    }
}

// ---------------------------------------------------------------------------
// Build X[r] = [ selfP[self_idx[r]] (256 bf16) | mean_f nbP[nb_idx[r*10+f]] ]
// One wave per row r. idx==nullptr means identity (r or r*10+f).
// ---------------------------------------------------------------------------
__global__ void build_x_k(u16* __restrict__ X, const u16* __restrict__ selfP,
                          const int* __restrict__ self_idx,
                          const u16* __restrict__ nbP,
                          const int* __restrict__ nb_idx, int R) {
    int w = (blockIdx.x * blockDim.x + threadIdx.x) >> 6;
    int lane = threadIdx.x & 63;
    if (w >= R) return;
    int c4 = lane * 4;
    int sr = self_idx ? self_idx[w] : w;
    ushort4 sv = *(const ushort4*)&selfP[(size_t)sr * 256 + c4];
    *(ushort4*)&X[(size_t)w * 512 + c4] = sv;

    float a0 = 0.f, a1 = 0.f, a2 = 0.f, a3 = 0.f;
    #pragma unroll
    for (int f = 0; f < 10; ++f) {
        int nr = nb_idx ? nb_idx[w * 10 + f] : w * 10 + f;
        ushort4 nv = *(const ushort4*)&nbP[(size_t)nr * 256 + c4];
        a0 += bf2f(nv.x); a1 += bf2f(nv.y); a2 += bf2f(nv.z); a3 += bf2f(nv.w);
    }
    ushort4 o;
    o.x = f2bf(a0 * 0.1f); o.y = f2bf(a1 * 0.1f);
    o.z = f2bf(a2 * 0.1f); o.w = f2bf(a3 * 0.1f);
    *(ushort4*)&X[(size_t)w * 512 + 256 + c4] = o;
}

// ---------------------------------------------------------------------------
// logits[b] = sum_k hu[b,k]*hi[b,k]*wlin[k] + blin    (one wave per b, 128 dims)
// ---------------------------------------------------------------------------
__global__ void logits_k(const float* __restrict__ hu, const float* __restrict__ hi,
                         const float* __restrict__ wlin, const float* __restrict__ blin,
                         float* __restrict__ out, int Bn) {
    int w = (blockIdx.x * blockDim.x + threadIdx.x) >> 6;
    int lane = threadIdx.x & 63;
    if (w >= Bn) return;
    float s = 0.f;
    #pragma unroll
    for (int k = lane; k < 128; k += 64)
        s += hu[(size_t)w * 128 + k] * hi[(size_t)w * 128 + k] * wlin[k];
    #pragma unroll
    for (int off = 32; off > 0; off >>= 1) s += __shfl_down(s, off, 64);
    if (lane == 0) out[w] = s + blin[0];
}

// ---------------------------------------------------------------------------
extern "C" void kernel_launch(void* const* d_in, const int* in_sizes, int n_in,
                              void* d_out, int out_size, void* d_ws, size_t ws_size,
                              hipStream_t stream) {
    const float* user_feat = (const float*)d_in[0];
    const float* item_feat = (const float*)d_in[1];
    const float* W_pu = (const float*)d_in[2];
    const float* b_pu = (const float*)d_in[3];
    const float* W_pi = (const float*)d_in[4];
    const float* b_pi = (const float*)d_in[5];
    const float* u_self0 = (const float*)d_in[6];
    const float* u_agg0 = (const float*)d_in[7];
    const float* u_self1 = (const float*)d_in[8];
    const float* u_agg1 = (const float*)d_in[9];
    const float* i_self0 = (const float*)d_in[10];
    const float* i_agg0 = (const float*)d_in[11];
    const float* i_self1 = (const float*)d_in[12];
    const float* i_agg1 = (const float*)d_in[13];
    const float* W_lin = (const float*)d_in[14];
    const float* b_lin = (const float*)d_in[15];
    const int* src_h0 = (const int*)d_in[16];
    const int* src_h1 = (const int*)d_in[17];
    const int* src_h2 = (const int*)d_in[18];
    const int* dst_h0 = (const int*)d_in[19];
    const int* dst_h1 = (const int*)d_in[20];
    const int* dst_h2 = (const int*)d_in[21];
    float* out = (float*)d_out;

    const int NU = 50000, NI = 100000, B = 4096, BF = 40960;

    char* ws = (char*)d_ws;
    size_t off = 0;
    auto alloc = [&](size_t bytes) -> void* {
        void* p = ws + off;
        off += (bytes + 255) & ~(size_t)255;
        return p;
    };
    u16* Pu  = (u16*)alloc((size_t)NU * 256 * 2);   // user projections, bf16
    u16* Pi  = (u16*)alloc((size_t)NI * 256 * 2);   // item projections, bf16
    u16* X1  = (u16*)alloc((size_t)BF * 512 * 2);   // [h1 | mean(h2)]  (reused per side)
    u16* G1  = (u16*)alloc((size_t)BF * 256 * 2);   // layer-0 hop-1 out (reused)
    u16* X0  = (u16*)alloc((size_t)B * 512 * 2);
    u16* G0  = (u16*)alloc((size_t)B * 256 * 2);
    u16* X2  = (u16*)alloc((size_t)B * 512 * 2);
    float* Hu = (float*)alloc((size_t)B * 128 * 4);
    float* Hi = (float*)alloc((size_t)B * 128 * 4);
    u16* WpuT = (u16*)alloc(256 * 512 * 2);
    u16* WpiT = (u16*)alloc(256 * 512 * 2);
    u16* W0uT = (u16*)alloc(256 * 512 * 2);
    u16* W0iT = (u16*)alloc(256 * 512 * 2);
    u16* W1uT = (u16*)alloc(128 * 512 * 2);
    u16* W1iT = (u16*)alloc(128 * 512 * 2);

    // --- weight prep (bf16, [N,512] transposed-concat layouts) ---
    transcat_k<<<512, 256, 0, stream>>>(WpuT, W_pu, W_pu, 256, 512);
    transcat_k<<<512, 256, 0, stream>>>(WpiT, W_pi, W_pi, 256, 512);
    transcat_k<<<512, 256, 0, stream>>>(W0uT, u_self0, u_agg0, 256, 256);
    transcat_k<<<512, 256, 0, stream>>>(W0iT, i_self0, i_agg0, 256, 256);
    transcat_k<<<256, 256, 0, stream>>>(W1uT, u_self1, u_agg1, 128, 256);
    transcat_k<<<256, 256, 0, stream>>>(W1iT, i_self1, i_agg1, 128, 256);

    // --- projections: P = sigmoid(feat @ W + b), bf16 out ---
    gemm_k<float, 2, u16><<<dim3((NU + BM - 1) / BM, 2), 256, 0, stream>>>(
        user_feat, WpuT, b_pu, Pu, NU, 256);
    gemm_k<float, 2, u16><<<dim3((NI + BM - 1) / BM, 2), 256, 0, stream>>>(
        item_feat, WpiT, b_pi, Pi, NI, 256);

    // --- user (src) side ---
    build_x_k<<<BF / 4, 256, 0, stream>>>(X1, Pi, src_h1, Pu, src_h2, BF);
    gemm_k<u16, 1, u16><<<dim3(BF / BM, 2), 256, 0, stream>>>(X1, W0uT, nullptr, G1, BF, 256);
    build_x_k<<<B / 4, 256, 0, stream>>>(X0, Pu, src_h0, Pi, src_h1, B);
    gemm_k<u16, 1, u16><<<dim3(B / BM, 2), 256, 0, stream>>>(X0, W0uT, nullptr, G0, B, 256);
    build_x_k<<<B / 4, 256, 0, stream>>>(X2, G0, nullptr, G1, nullptr, B);
    gemm_k<u16, 0, float><<<dim3(B / BM, 1), 256, 0, stream>>>(X2, W1uT, nullptr, Hu, B, 128);

    // --- item (dst) side ---
    build_x_k<<<BF / 4, 256, 0, stream>>>(X1, Pu, dst_h1, Pi, dst_h2, BF);
    gemm_k<u16, 1, u16><<<dim3(BF / BM, 2), 256, 0, stream>>>(X1, W0iT, nullptr, G1, BF, 256);
    build_x_k<<<B / 4, 256, 0, stream>>>(X0, Pi, dst_h0, Pu, dst_h1, B);
    gemm_k<u16, 1, u16><<<dim3(B / BM, 2), 256, 0, stream>>>(X0, W0iT, nullptr, G0, B, 256);
    build_x_k<<<B / 4, 256, 0, stream>>>(X2, G0, nullptr, G1, nullptr, B);
    gemm_k<u16, 0, float><<<dim3(B / BM, 1), 256, 0, stream>>>(X2, W1iT, nullptr, Hi, B, 128);

    // --- final logits ---
    logits_k<<<B / 4, 256, 0, stream>>>(Hu, Hi, W_lin, b_lin, out, B);
}